// Round 2
// baseline (201.263 us; speedup 1.0000x reference)
//
#include <hip/hip_runtime.h>

namespace {
constexpr int S = 1024;
constexpr int B = 32;
constexpr int OFF = 256;               // (S-H)/2 = (S-W)/2
constexpr int NPIX = B * 512 * 512;    // 8,388,608 pixels
constexpr int NF4  = NPIX * 3 / 4;     // 6,291,456 float4 of image data
constexpr size_t MASK_BYTES = (size_t)NPIX * 4;  // 33.55 MB in d_ws

typedef float f32x4 __attribute__((ext_vector_type(4)));

// stripe indicator as float {0,1}; exact int div by runtime gb via float
// reciprocal estimate + one-step fixup
__device__ __forceinline__ float stripef(int i, int start, int gb, int len, int n, float inv_gb) {
    const int d = i - start;
    int q = (int)((float)d * inv_gb);
    int r = d - q * gb;
    if (r < 0)        { r += gb; --q; }
    else if (r >= gb) { r -= gb; ++q; }
    return (d >= 0 && r < len && q < n) ? 1.0f : 0.0f;
}

// ---------------- Pass 1: per-pixel mask -> d_ws (33.5 MB) ----------------
// 512 blocks x 256 thr: 16 blocks per image, each covers 32 rows (4096 float4).
// Arithmetic identical to the round-1 passing kernel (separable closed form:
// m = cx + ry - cx*ry; reflection provably identity for this angle range).
__global__ __launch_bounds__(256) void mask_kernel(
    const float* __restrict__ angles,
    const int* __restrict__ gridblock,
    const int* __restrict__ start1,
    const int* __restrict__ start2,
    float* __restrict__ mask)
{
    __shared__ float2 colsAD[1024];
    __shared__ float2 rowsAD[1024];

    const int tid = threadIdx.x;
    const int img = blockIdx.x >> 4;
    const int seg = blockIdx.x & 15;

    const float ang = angles[img];
    const int gb = gridblock[img];
    const int s1 = start1[img];
    const int s2 = start2[img];

    const float gbf = (float)gb;
    // match numpy's two-step f32 rounding exactly: no FMA contraction
    int len = (int)(__fadd_rn(__fmul_rn(gbf, 0.6f), 0.5f));
    len = min(max(len, 1), gb - 1);
    const int n = S / gb;
    const float inv_gb = 1.0f / gbf;

    {   // LUT build: thread t fills entries 4t..4t+3 of both tables
        const int i0 = tid << 2;
        float rv[5], cv[5];
#pragma unroll
        for (int i = 0; i < 5; ++i) {
            rv[i] = stripef(i0 + i, s1, gb, len, n, inv_gb);
            cv[i] = stripef(i0 + i, s2, gb, len, n, inv_gb);
        }
#pragma unroll
        for (int i = 0; i < 4; ++i) {
            rowsAD[i0 + i] = make_float2(rv[i], rv[i + 1] - rv[i]);
            colsAD[i0 + i] = make_float2(cv[i], cv[i + 1] - cv[i]);
        }
    }
    __syncthreads();

    float sn, cs;
    sincosf(ang, &sn, &cs);
    const float c = (float)(S - 1) * 0.5f;   // 511.5

    float4* __restrict__ mask4 = (float4*)mask + (size_t)img * 65536 + (size_t)seg * 4096;

#pragma unroll
    for (int k = 0; k < 16; ++k) {
        const int f4  = (k << 8) + tid;            // [0,4096) within segment
        const int pix = (((seg << 12) + f4) << 2); // pixel within image
        const int y = pix >> 9;
        const int x = pix & 511;                   // multiple of 4, all 4 px in one row
        const float Y = (float)(y + OFF) - c;
        float m[4];
#pragma unroll
        for (int i = 0; i < 4; ++i) {
            const float X  = (float)(x + i + OFF) - c;
            const float sx = cs * X + sn * Y + c;
            const float sy = cs * Y - sn * X + c;
            const float x0f = floorf(sx);
            const float y0f = floorf(sy);
            const float fx = sx - x0f;
            const float fy = sy - y0f;
            const float2 cad = colsAD[(int)x0f];   // in [154,868] — no clamp needed
            const float2 rad = rowsAD[(int)y0f];
            const float cx = fmaf(fx, cad.y, cad.x);
            const float ry = fmaf(fy, rad.y, rad.x);
            m[i] = cx + ry - cx * ry;
        }
        mask4[f4] = make_float4(m[0], m[1], m[2], m[3]);
    }
}

// ---------------- Pass 2: barrier-free streaming multiply ----------------
// 4096 blocks x 256 thr, 6 float4/thread, all loads issued up front.
__global__ __launch_bounds__(256) void mul_kernel(
    const float* __restrict__ images,
    const float* __restrict__ mask,
    float* __restrict__ out)
{
    const int t = blockIdx.x * 256 + threadIdx.x;  // [0, 1048576)
    const float4* __restrict__ in4 = (const float4*)images;
    f32x4* __restrict__ out4 = (f32x4*)out;

    float4 p[6];
    float ma[6], mb[6];
    int r3[6];
#pragma unroll
    for (int j = 0; j < 6; ++j) {
        const int idx = t + (j << 20);
        p[j] = in4[idx];
        const unsigned lf = (unsigned)idx << 2;            // global float index
        const unsigned q = __umulhi(lf, 0xAAAAAAABu) >> 1; // floor(lf/3)
        r3[j] = (int)(lf - q * 3u);
        ma[j] = mask[q];
        mb[j] = mask[q + 1];
    }
#pragma unroll
    for (int j = 0; j < 6; ++j) {
        const int idx = t + (j << 20);
        // component c belongs to pixel q + ((r+c) >= 3)
        const float m1 = (r3[j] == 2) ? mb[j] : ma[j];
        const float m2 = (r3[j] != 0) ? mb[j] : ma[j];
        f32x4 o;
        o.x = p[j].x * ma[j];
        o.y = p[j].y * m1;
        o.z = p[j].z * m2;
        o.w = p[j].w * mb[j];
        __builtin_nontemporal_store(o, out4 + idx);
    }
}

// ---------------- Fallback: round-1 single kernel (if ws too small) ----------------
__global__ __launch_bounds__(512) void gridmask_kernel(
    const float* __restrict__ images,
    const float* __restrict__ angles,
    const int* __restrict__ gridblock,
    const int* __restrict__ start1,
    const int* __restrict__ start2,
    float* __restrict__ out)
{
    __shared__ float2 colsAD[1024];
    __shared__ float2 rowsAD[1024];
    __shared__ float  mlds[4096];

    const int tid = threadIdx.x;
    const int blk = blockIdx.x;
    const int b   = blk >> 6;
    const int y0  = (blk & 63) << 3;

    const size_t fbase = (size_t)blk * 12288;
    const float4* __restrict__ gin4 = (const float4*)(images + fbase);
    float4 p[6];
#pragma unroll
    for (int j = 0; j < 6; ++j) p[j] = gin4[(j << 9) + tid];

    const float ang = angles[b];
    const int gb = gridblock[b];
    const int s1 = start1[b];
    const int s2 = start2[b];

    const float gbf = (float)gb;
    int len = (int)(__fadd_rn(__fmul_rn(gbf, 0.6f), 0.5f));
    len = min(max(len, 1), gb - 1);
    const int n = S / gb;
    const float inv_gb = 1.0f / gbf;

    {
        const int i0 = tid << 1;
        const float r0 = stripef(i0,     s1, gb, len, n, inv_gb);
        const float r1 = stripef(i0 + 1, s1, gb, len, n, inv_gb);
        const float r2 = stripef(i0 + 2, s1, gb, len, n, inv_gb);
        rowsAD[i0]     = make_float2(r0, r1 - r0);
        rowsAD[i0 + 1] = make_float2(r1, r2 - r1);
        const float c0 = stripef(i0,     s2, gb, len, n, inv_gb);
        const float c1 = stripef(i0 + 1, s2, gb, len, n, inv_gb);
        const float c2 = stripef(i0 + 2, s2, gb, len, n, inv_gb);
        colsAD[i0]     = make_float2(c0, c1 - c0);
        colsAD[i0 + 1] = make_float2(c1, c2 - c1);
    }
    __syncthreads();

    {
        float sn, cs;
        sincosf(ang, &sn, &cs);
        const float c = (float)(S - 1) * 0.5f;
        const float X = (float)(tid + OFF) - c;
#pragma unroll
        for (int r = 0; r < 8; ++r) {
            const float Yr = (float)(y0 + r + OFF) - c;
            const float sx = cs * X + sn * Yr + c;
            const float sy = cs * Yr - sn * X + c;
            const float x0f = floorf(sx);
            const float y0f = floorf(sy);
            const float fx = sx - x0f;
            const float fy = sy - y0f;
            const float2 cad = colsAD[(int)x0f];
            const float2 rad = rowsAD[(int)y0f];
            const float cx = fmaf(fx, cad.y, cad.x);
            const float ry = fmaf(fy, rad.y, rad.x);
            mlds[(r << 9) + tid] = cx + ry - cx * ry;
        }
    }
    __syncthreads();

    f32x4* __restrict__ gout4 = (f32x4*)(out + fbase);
#pragma unroll
    for (int j = 0; j < 6; ++j) {
        const int lf = (j << 11) + (tid << 2);
        const int q  = lf / 3;
        const int r  = lf - q * 3;
        const float ma = mlds[q];
        const float mb = mlds[min(q + 1, 4095)];
        const float m0 = ma;
        const float m1 = (r + 1 >= 3) ? mb : ma;
        const float m2 = (r + 2 >= 3) ? mb : ma;
        const float m3 = (r + 3 >= 3) ? mb : ma;
        f32x4 o;
        o.x = p[j].x * m0;
        o.y = p[j].y * m1;
        o.z = p[j].z * m2;
        o.w = p[j].w * m3;
        __builtin_nontemporal_store(o, gout4 + (j << 9) + tid);
    }
}
} // namespace

extern "C" void kernel_launch(void* const* d_in, const int* in_sizes, int n_in,
                              void* d_out, int out_size, void* d_ws, size_t ws_size,
                              hipStream_t stream) {
    const float* images    = (const float*)d_in[0];
    const float* angles    = (const float*)d_in[1];
    const int*   gridblock = (const int*)d_in[2];
    const int*   start1    = (const int*)d_in[3];
    const int*   start2    = (const int*)d_in[4];
    float* outp = (float*)d_out;

    if (d_ws != nullptr && ws_size >= MASK_BYTES) {
        float* maskp = (float*)d_ws;
        mask_kernel<<<512, 256, 0, stream>>>(angles, gridblock, start1, start2, maskp);
        mul_kernel<<<NF4 / (6 * 256), 256, 0, stream>>>(images, maskp, outp);
    } else {
        // fallback: proven single-kernel path
        gridmask_kernel<<<2048, 512, 0, stream>>>(images, angles, gridblock, start1, start2, outp);
    }
}

// Round 3
// 184.464 us; speedup vs baseline: 1.0911x; 1.0911x over previous
//
#include <hip/hip_runtime.h>

namespace {
constexpr int S = 1024;
constexpr int B = 32;
constexpr int OFF = 256; // (S-H)/2 = (S-W)/2

typedef float f32x4 __attribute__((ext_vector_type(4)));

// stripe indicator as float {0,1}; exact int div by runtime gb via float
// reciprocal estimate + one-step fixup (identical to all passing rounds)
__device__ __forceinline__ float stripef(int i, int start, int gb, int len, int n, float inv_gb) {
    const int d = i - start;
    int q = (int)((float)d * inv_gb);
    int r = d - q * gb;
    if (r < 0)        { r += gb; --q; }
    else if (r >= gb) { r -= gb; ++q; }
    return (d >= 0 && r < len && q < n) ? 1.0f : 0.0f;
}

// Single fused kernel: 4096 blocks x 256 thr; block covers 1536 contiguous
// float4 (24 KB) of one image; 128 blocks per image.
// Structure: issue all 6 global loads -> build separable LUTs (LDS, one
// barrier) -> per float4 compute mask INLINE (rotation + 2 LUT lerps,
// separable closed form m = cx + ry - cx*ry) -> multiply -> plain store.
// No mask LDS stage, no second barrier, no mask HBM stream: the VALU mask
// work sits between load-issue and store so the memory pipeline is covered
// continuously instead of burst-phased.
__global__ __launch_bounds__(256) void gridmask_kernel(
    const float* __restrict__ images,
    const float* __restrict__ angles,
    const int* __restrict__ gridblock,
    const int* __restrict__ start1,
    const int* __restrict__ start2,
    float* __restrict__ out)
{
    __shared__ float2 colsAD[1024];   // {v[i], v[i+1]-v[i]}
    __shared__ float2 rowsAD[1024];

    const int tid = threadIdx.x;
    const int blk = blockIdx.x;          // 4096 blocks
    const int b   = blk >> 7;            // 128 blocks per image

    // ---- issue the 6 image loads immediately (HBM latency hides under
    // the LUT build + mask math; no dependence until the final multiply) ----
    const size_t f4base = (size_t)b * 196608 + (size_t)(blk & 127) * 1536;
    const float4* __restrict__ gin4 = (const float4*)images + f4base;
    float4 p[6];
#pragma unroll
    for (int j = 0; j < 6; ++j) p[j] = gin4[(j << 8) + tid];

    const float ang = angles[b];
    const int gb = gridblock[b];
    const int s1 = start1[b];
    const int s2 = start2[b];

    const float gbf = (float)gb;
    // match numpy's two-step f32 rounding exactly: no FMA contraction
    int len = (int)(__fadd_rn(__fmul_rn(gbf, 0.6f), 0.5f));
    len = min(max(len, 1), gb - 1);
    const int n = S / gb;
    const float inv_gb = 1.0f / gbf;

    {   // LUT build: thread t fills entries 4t..4t+3 of both tables
        const int i0 = tid << 2;
        float rv[5], cv[5];
#pragma unroll
        for (int i = 0; i < 5; ++i) {
            rv[i] = stripef(i0 + i, s1, gb, len, n, inv_gb);
            cv[i] = stripef(i0 + i, s2, gb, len, n, inv_gb);
        }
#pragma unroll
        for (int i = 0; i < 4; ++i) {
            rowsAD[i0 + i] = make_float2(rv[i], rv[i + 1] - rv[i]);
            colsAD[i0 + i] = make_float2(cv[i], cv[i + 1] - cv[i]);
        }
    }
    __syncthreads();

    float sn, cs;
    sincosf(ang, &sn, &cs);
    const float c = (float)(S - 1) * 0.5f;   // 511.5

    const unsigned wbase = ((unsigned)(blk & 127) * 1536u) << 2; // within-image float base

    f32x4* __restrict__ gout4 = (f32x4*)out + f4base;

#pragma unroll
    for (int j = 0; j < 6; ++j) {
        const int lf4 = (j << 8) + tid;                  // [0,1536)
        const unsigned wlf = wbase + ((unsigned)lf4 << 2);      // within-image float idx
        const unsigned q = __umulhi(wlf, 0xAAAAAAABu) >> 1;     // floor(wlf/3), pixel idx
        const int r = (int)(wlf - q * 3u);
        // inline mask for pixels q and q+1 (q+1 never exceeds image: last
        // float4 has q = 262142). Reflection provably identity for this
        // angle range (sx,sy in [154.5, 868.5]) — no clamp on LUT indices.
        float mm[2];
#pragma unroll
        for (int k = 0; k < 2; ++k) {
            const unsigned qq = q + (unsigned)k;
            const int y = (int)(qq >> 9);
            const int x = (int)(qq & 511u);
            const float X = (float)(x + OFF) - c;
            const float Y = (float)(y + OFF) - c;
            const float sx = cs * X + sn * Y + c;
            const float sy = cs * Y - sn * X + c;
            const float x0f = floorf(sx);
            const float y0f = floorf(sy);
            const float fx = sx - x0f;
            const float fy = sy - y0f;
            const float2 cad = colsAD[(int)x0f];
            const float2 rad = rowsAD[(int)y0f];
            const float cxv = fmaf(fx, cad.y, cad.x);
            const float ryv = fmaf(fy, rad.y, rad.x);
            mm[k] = cxv + ryv - cxv * ryv;
        }
        const float ma = mm[0], mb = mm[1];
        // component c belongs to pixel q + ((r+c) >= 3)
        const float m1 = (r == 2) ? mb : ma;
        const float m2 = (r != 0) ? mb : ma;
        f32x4 o;
        o.x = p[j].x * ma;
        o.y = p[j].y * m1;
        o.z = p[j].z * m2;
        o.w = p[j].w * mb;
        gout4[lf4] = o;   // plain (cached) store — matches the 6.8 TB/s fill path
    }
}
} // namespace

extern "C" void kernel_launch(void* const* d_in, const int* in_sizes, int n_in,
                              void* d_out, int out_size, void* d_ws, size_t ws_size,
                              hipStream_t stream) {
    const float* images    = (const float*)d_in[0];
    const float* angles    = (const float*)d_in[1];
    const int*   gridblock = (const int*)d_in[2];
    const int*   start1    = (const int*)d_in[3];
    const int*   start2    = (const int*)d_in[4];
    float* outp = (float*)d_out;

    // 4096 blocks x 256 threads; each block: 1536 contiguous float4 of one image
    gridmask_kernel<<<4096, 256, 0, stream>>>(images, angles, gridblock, start1, start2, outp);
}